// Round 3
// baseline (181.252 us; speedup 1.0000x reference)
//
#include <hip/hip_runtime.h>
#include <math.h>

// ---------------------------------------------------------------------------
// LTFGW: N=4096, K=16 (k1=17), T=16, NT=16, D=128, OUTER=3, INNER=5.
//
// R8: R7 post-mortem — outer row-skip branch fired, but the inner masked sum
//     compiled to 17 uniform s_cbranch per nonzero row (VALU-busy 60us > R5's
//     54us). Fix: branchless inner — {0,1.0f} multiplier built in the SCALAR
//     pipe (s_cselect of 0x3f800000) feeding v_fmac with an SGPR operand ->
//     1 VALU/element, zero branches, bit-exact (x*1.0 / x*0.0 exact).
//     Plus: Sinkhorn w/sg 16-deep serial fmac chains split into 4 partials
//     (latency at ~34% occupancy), and LDS 21504->20360 B (merged U/V buffer,
//     TSTR 300) to raise the blocks/CU ceiling 7->8.
// R7 (kept): real uniform outer branch via volatile-asm pin on rmi.
// R6 (kept): binary adj -> packed 2MB bitset; cc1 = popcount/17.
// R2/R3 lesson (kept): no bulk LDS vector loads inside unrolled branches.
// ---------------------------------------------------------------------------

#define NN 4096
#define KNB 16
#define K1 17
#define TSTR 300      // Ksh per-template stride; 300%32==12 -> ~2-way banks
#define TINYF 1e-16f

typedef const __attribute__((address_space(4))) float* c4fp;
typedef const __attribute__((address_space(4))) int*   c4ip;
__device__ __forceinline__ float sload(const float* p){ return *(c4fp)(unsigned long long)p; }
__device__ __forceinline__ int   sloadi(const int* p) { return *(c4ip)(unsigned long long)p; }

template<int CTRL>
__device__ __forceinline__ float dppmov(float x) {
  return __int_as_float(
      __builtin_amdgcn_update_dpp(0, __float_as_int(x), CTRL, 0xF, 0xF, true));
}
__device__ __forceinline__ float xor4v(float x) {        // xor4 = xor7 then xor3
  return dppmov<0x1B>(dppmov<0x141>(x));
}
__device__ __forceinline__ float rsum16(float x) {
  x += dppmov<0xB1>(x); x += dppmov<0x4E>(x);
  x += xor4v(x);        x += dppmov<0x128>(x);
  return x;
}
__device__ __forceinline__ float rmin16(float x) {
  x = fminf(x, dppmov<0xB1>(x)); x = fminf(x, dppmov<0x4E>(x));
  x = fminf(x, xor4v(x));        x = fminf(x, dppmov<0x128>(x));
  return x;
}
__device__ __forceinline__ float rmax16(float x) {
  x = fmaxf(x, dppmov<0xB1>(x)); x = fmaxf(x, dppmov<0x4E>(x));
  x = fmaxf(x, xor4v(x));        x = fmaxf(x, dppmov<0x128>(x));
  return x;
}
__device__ __forceinline__ float rcpn(float x) {   // rcp + 1 Newton step
  float r = __builtin_amdgcn_rcpf(x);
  return r * (2.f - x * r);
}
// {0,1} bit -> float 0.0/1.0 via scalar pipe (s_cselect), no branch, no VALU.
__device__ __forceinline__ float mbit(int m, int j) {
  return __int_as_float((m & (1 << j)) ? 0x3f800000 : 0);
}

// cumulative XOR walk (verified R1/R4, absmax 0): after step r, g = src lane l^r
#define WSTEP(C, R) { g = dppmov<C>(g); acc = fmaf(g, c2reg[R], acc); }
#define WALK15() \
  WSTEP(0xB1,1)  WSTEP(0x1B,2)  WSTEP(0xB1,3)  WSTEP(0x141,4) \
  WSTEP(0xB1,5)  WSTEP(0x1B,6)  WSTEP(0xB1,7)  WSTEP(0x140,8) \
  WSTEP(0xB1,9)  WSTEP(0x1B,10) WSTEP(0xB1,11) WSTEP(0x141,12) \
  WSTEP(0xB1,13) WSTEP(0x1B,14) WSTEP(0xB1,15)

// masked row-sum over Gcol (binary C1 row, SGPR mask), branchless, 2 chains
#define MASKED_ROWSUM(rmi, OUT) \
  float s0_ = 0.f, s1_ = 0.f; \
  s0_ = fmaf(mbit(rmi, 0), Gcol[ 0], s0_); s1_ = fmaf(mbit(rmi, 1), Gcol[ 1], s1_); \
  s0_ = fmaf(mbit(rmi, 2), Gcol[ 2], s0_); s1_ = fmaf(mbit(rmi, 3), Gcol[ 3], s1_); \
  s0_ = fmaf(mbit(rmi, 4), Gcol[ 4], s0_); s1_ = fmaf(mbit(rmi, 5), Gcol[ 5], s1_); \
  s0_ = fmaf(mbit(rmi, 6), Gcol[ 6], s0_); s1_ = fmaf(mbit(rmi, 7), Gcol[ 7], s1_); \
  s0_ = fmaf(mbit(rmi, 8), Gcol[ 8], s0_); s1_ = fmaf(mbit(rmi, 9), Gcol[ 9], s1_); \
  s0_ = fmaf(mbit(rmi,10), Gcol[10], s0_); s1_ = fmaf(mbit(rmi,11), Gcol[11], s1_); \
  s0_ = fmaf(mbit(rmi,12), Gcol[12], s0_); s1_ = fmaf(mbit(rmi,13), Gcol[13], s1_); \
  s0_ = fmaf(mbit(rmi,14), Gcol[14], s0_); s1_ = fmaf(mbit(rmi,15), Gcol[15], s1_); \
  s0_ = fmaf(mbit(rmi,16), Gcol[16], s0_); \
  float OUT = s0_ + s1_;

// ---------------------------------------------------------------------------
// prep_combined: one dispatch, block-range partitioned (unchanged from R7).
// ---------------------------------------------------------------------------
#define PG_GEMM  256
#define PG_XSQ   (PG_GEMM + 1024)       // 1280
#define PG_SCAL  PG_XSQ                  // block 1280
#define PG_ADJ   (PG_SCAL + 1)           // 1281
#define PG_TOT   (PG_ADJ + 2048)         // 3329

__global__ __launch_bounds__(256) void prep_combined(
    const float* __restrict__ x, const float* __restrict__ adj,
    const int* __restrict__ neighbors, const float* __restrict__ templates_,
    const float* __restrict__ tf, const float* __restrict__ q0,
    const float* __restrict__ alpha0,
    float* __restrict__ P, unsigned* __restrict__ adjbits,
    float* __restrict__ xsq,
    float* __restrict__ tfsq, float* __restrict__ qmat, float* __restrict__ cq,
    float* __restrict__ walpha) {
  __shared__ __align__(16) float smem[2 * 64 * 68];   // 34816 B arena (gemm)
  const int b = blockIdx.x, tid = threadIdx.x;

  if (b < PG_GEMM) {
    // ---- pgemm: 64x64 tile, 4x4 per thread ----
    float (*As)[68] = (float (*)[68])smem;
    float (*Bs)[68] = (float (*)[68])(smem + 64 * 68);
    int tx = tid & 15, ty = tid >> 4;
    int r0 = (b & 63) * 64, c0 = (b >> 6) * 64;
    float acc[4][4] = {};
    for (int h = 0; h < 2; ++h) {
      __syncthreads();
#pragma unroll
      for (int q = 0; q < 4; ++q) {
        int f = tid + 256*q;
        int row = f >> 4, d4 = (f & 15) << 2;
        float4 a = *(const float4*)&x[(r0+row)*128 + h*64 + d4];
        As[d4+0][row]=a.x; As[d4+1][row]=a.y; As[d4+2][row]=a.z; As[d4+3][row]=a.w;
        float4 bb = *(const float4*)&tf[(c0+row)*128 + h*64 + d4];
        Bs[d4+0][row]=bb.x; Bs[d4+1][row]=bb.y; Bs[d4+2][row]=bb.z; Bs[d4+3][row]=bb.w;
      }
      __syncthreads();
#pragma unroll
      for (int d = 0; d < 64; ++d) {
        float4 a = *(const float4*)&As[d][ty*4];
        float4 bb = *(const float4*)&Bs[d][tx*4];
        float av[4]={a.x,a.y,a.z,a.w}, bv[4]={bb.x,bb.y,bb.z,bb.w};
#pragma unroll
        for (int i = 0; i < 4; ++i)
#pragma unroll
          for (int j = 0; j < 4; ++j) acc[i][j] = fmaf(av[i], bv[j], acc[i][j]);
      }
    }
#pragma unroll
    for (int i = 0; i < 4; ++i) {
      float4 o; o.x=acc[i][0]; o.y=acc[i][1]; o.z=acc[i][2]; o.w=acc[i][3];
      *(float4*)&P[(r0 + ty*4 + i)*256 + c0 + tx*4] = o;
    }
    return;
  }

  if (b < PG_XSQ) {
    // ---- xsq: 4 rows per block, 1 wave per row ----
    int n = (b - PG_GEMM)*4 + (tid >> 6), lane = tid & 63;
    float2 v = *(const float2*)&x[n*128 + lane*2];
    float s = fmaf(v.x, v.x, v.y*v.y);
    s += __shfl_xor(s,1); s += __shfl_xor(s,2);  s += __shfl_xor(s,4);
    s += __shfl_xor(s,8); s += __shfl_xor(s,16); s += __shfl_xor(s,32);
    if (lane == 0) xsq[n] = s;
    return;
  }

  if (b == PG_SCAL) {
    // ---- scalars: alpha, q=softmax(q0), cq, tfsq ----
    int t = tid >> 4, l = tid & 15;
    if (tid == 0) walpha[0] = 1.f / (1.f + expf(-alpha0[0]));
    float qr[16]; float mx = -3.0e38f;
#pragma unroll
    for (int m = 0; m < 16; ++m) { qr[m] = q0[t*16+m]; mx = fmaxf(mx, qr[m]); }
    float s = 0.f;
#pragma unroll
    for (int m = 0; m < 16; ++m) { qr[m] = expf(qr[m]-mx); s += qr[m]; }
    float inv = 1.f / s;
    qmat[tid] = qr[l] * inv;
    float c = 0.f;
#pragma unroll
    for (int m = 0; m < 16; ++m) {
      float c2 = templates_[t*256 + l*16 + m];
      c = fmaf(qr[m]*inv, c2*c2, c);
    }
    cq[tid] = c;
    float ts = 0.f;
#pragma unroll
    for (int dq = 0; dq < 32; ++dq) {
      float4 v = *(const float4*)&tf[tid*128 + dq*4];
      ts = fmaf(v.x,v.x,ts); ts = fmaf(v.y,v.y,ts);
      ts = fmaf(v.z,v.z,ts); ts = fmaf(v.w,v.w,ts);
    }
    tfsq[tid] = ts;
    return;
  }

  // ---- adjbits: 2 adj rows per block, coalesced stream -> packed bits ----
  {
    int row0 = (b - PG_ADJ) * 2;
    const float4* a0 = (const float4*)&adj[(long long)row0 * NN];
    const float4* a1 = (const float4*)&adj[(long long)(row0 + 1) * NN];
    float4 v0[4], v1[4];
#pragma unroll
    for (int q = 0; q < 4; ++q) v0[q] = a0[tid*4 + q];
#pragma unroll
    for (int q = 0; q < 4; ++q) v1[q] = a1[tid*4 + q];
    unsigned m0 = 0, m1 = 0;
#pragma unroll
    for (int q = 0; q < 4; ++q) {
      m0 |= (unsigned)(v0[q].x != 0.f) << (q*4 + 0);
      m0 |= (unsigned)(v0[q].y != 0.f) << (q*4 + 1);
      m0 |= (unsigned)(v0[q].z != 0.f) << (q*4 + 2);
      m0 |= (unsigned)(v0[q].w != 0.f) << (q*4 + 3);
      m1 |= (unsigned)(v1[q].x != 0.f) << (q*4 + 0);
      m1 |= (unsigned)(v1[q].y != 0.f) << (q*4 + 1);
      m1 |= (unsigned)(v1[q].z != 0.f) << (q*4 + 2);
      m1 |= (unsigned)(v1[q].w != 0.f) << (q*4 + 3);
    }
    unsigned o0 = (unsigned)__shfl_xor((int)m0, 1);
    unsigned o1 = (unsigned)__shfl_xor((int)m1, 1);
    if ((tid & 1) == 0) {
      adjbits[row0*128 + (tid >> 1)]       = m0 | (o0 << 16);
      adjbits[(row0 + 1)*128 + (tid >> 1)] = m1 | (o1 << 16);
    }
  }
}

// ---------------------------------------------------------------------------
// main: 1 block/node, 256 thr = 16 templates x 16 cols.
// LDS: Ksh 19200 + UVsh 1024 + nb/rm 136 = 20360 B -> 8 blocks/CU ceiling.
// ---------------------------------------------------------------------------
__global__ __launch_bounds__(256, 2) void ltfgw_main(
    const float* __restrict__ P, const unsigned* __restrict__ adjbits,
    const float* __restrict__ xsq, const float* __restrict__ tfsq,
    const float* __restrict__ qmat, const float* __restrict__ cq,
    const float* __restrict__ walpha, const int* __restrict__ neighbors,
    const float* __restrict__ templates_, float* __restrict__ out) {
  __shared__ __align__(16) float Ksh[16 * TSTR];
  __shared__ __align__(16) float UVsh[256];   // U and V time-share (wave-local)
  __shared__ int nb_sh[K1];
  __shared__ int rm_sh[K1];

  const int tid = threadIdx.x;
  const int t = tid >> 4, l = tid & 15;
  const int n = blockIdx.x;

  // ---- prologue: build 17 per-row C1 bitmasks from the packed bitset ----
  if (tid < K1) {
    nb_sh[tid] = (tid == 0) ? n : neighbors[n*KNB + tid - 1];
    rm_sh[tid] = 0;
  }
  __syncthreads();
  for (unsigned e = tid; e < 289; e += 256) {
    unsigned i = e / 17u, j = e % 17u;
    int ni = nb_sh[i], nj = nb_sh[j];
    unsigned w = adjbits[ni*128 + (nj >> 5)];
    if ((w >> (nj & 31)) & 1u) atomicOr(&rm_sh[i], 1 << j);
  }
  __syncthreads();

  int rm[K1];
  int nbk[K1];
#pragma unroll
  for (int k = 0; k < K1; ++k) {
    rm[k]  = __builtin_amdgcn_readfirstlane(rm_sh[k]);
    nbk[k] = __builtin_amdgcn_readfirstlane(nb_sh[k]);
  }

  const float alpha = sload(walpha);
  const float oma = 1.f - alpha;
  const float na2 = -2.f * alpha;

  const float tfsq_l = tfsq[tid];
  const float cq_l   = cq[tid];
  const float q_l    = qmat[tid];

  // Mcol = (1-a)*M + a*cC ; cc1 = popcount(row)/17 since C1 is binary.
  float Mcol[K1];
#pragma unroll
  for (int k = 0; k < K1; ++k) {
    float xs  = sload(xsq + nbk[k]);
    float cc1 = (float)__popc((unsigned)rm[k]) * (1.f/17.f);
    float pv  = P[nbk[k]*256 + tid];
    Mcol[k] = oma * (xs + tfsq_l - 2.f*pv) + alpha * (cc1 + cq_l);
  }

  // c2reg[r] = -2a * C2[t][l][l^r]  (pre-rotated for the XOR walk)
  float c2reg[16];
#pragma unroll
  for (int r = 0; r < 16; ++r)
    c2reg[r] = na2 * templates_[t*256 + l*16 + (l ^ r)];

  // G[j][l] in registers; init p*q
  float Gcol[K1];
#pragma unroll
  for (int j = 0; j < K1; ++j) Gcol[j] = (1.f/17.f) * q_l;

  const int tb = t * TSTR;
  float ur[16], u16 = 0.f, vm = 1.f;

#pragma unroll 1
  for (int outer = 0; outer < 3; ++outer) {
    // grad rows -> Kc[]; only C1-nonzero rows (~2.3/17) do bit-sum + walk.
    // Outer branch is real (volatile-asm pin, uniform SGPR mask); inner sum
    // is branchless: scalar-pipe {0,1.0f} multiplier + v_fmac (1 VALU/elem).
    float Kc[K1];
    float lo = 3.0e38f, hi = -3.0e38f;
#pragma unroll
    for (int i = 0; i < K1; ++i) {
      float gr = Mcol[i];
      int rmi = rm[i];
      if (rmi) {
        asm volatile("" : "+s"(rmi));
        MASKED_ROWSUM(rmi, s)
        float g = s, acc = s * c2reg[0];
        WALK15()
        gr += acc;
      }
      Kc[i] = gr;
      lo = fminf(lo, gr); hi = fmaxf(hi, gr);
    }
    lo = rmin16(lo); hi = rmax16(hi);
    float eps = 0.1f * (hi - lo) + TINYF;
    float sc = 1.4426950408889634f * __builtin_amdgcn_rcpf(eps);
    float nsc = -sc, losc = lo * sc;
#pragma unroll
    for (int i = 0; i < K1; ++i) {
      Kc[i] = __builtin_amdgcn_exp2f(fmaf(Kc[i], nsc, losc));
      Ksh[tb + i*17 + l] = Kc[i];           // transpose write (same wave)
    }
    // row l of K for the u-update
    float Krow[16];
#pragma unroll
    for (int jq = 0; jq < 4; ++jq) {
      float4 v = *(const float4*)&Ksh[tb + l*17 + jq*4];
      Krow[jq*4+0]=v.x; Krow[jq*4+1]=v.y; Krow[jq*4+2]=v.z; Krow[jq*4+3]=v.w;
    }

    // Sinkhorn: 5 iters (u then v), v0 = 1. U and V time-share UVsh:
    // write U -> read U (same wave, lgkmcnt-ordered) -> write V -> read V
    // next iter. Each 16-float segment is touched by exactly one wave.
    float vlane = 1.f;
    UVsh[tid] = 1.f;
#pragma unroll 1
    for (int it = 0; it < 5; ++it) {
      float vr[16];
#pragma unroll
      for (int q = 0; q < 4; ++q) {
        float4 v = *(const float4*)&UVsh[t*16 + q*4];
        vr[q*4+0]=v.x; vr[q*4+1]=v.y; vr[q*4+2]=v.z; vr[q*4+3]=v.w;
      }
      // 4 partial chains (17x4-cyc serial fmac -> ~5x4) for latency
      float w0=0.f, w1=0.f, w2=0.f, w3=0.f;
#pragma unroll
      for (int j = 0; j < 4; ++j) {
        w0 = fmaf(Krow[j],    vr[j],    w0);
        w1 = fmaf(Krow[j+4],  vr[j+4],  w1);
        w2 = fmaf(Krow[j+8],  vr[j+8],  w2);
        w3 = fmaf(Krow[j+12], vr[j+12], w3);
      }
      float w = (w0 + w1) + (w2 + w3);
      float w16 = rsum16(Kc[16] * vlane);          // row 16 via DPP
      float um = (1.f/17.f) * rcpn(fmaxf(w,   TINYF));
      u16      = (1.f/17.f) * rcpn(fmaxf(w16, TINYF));
      UVsh[tid] = um;
#pragma unroll
      for (int q = 0; q < 4; ++q) {
        float4 v = *(const float4*)&UVsh[t*16 + q*4];
        ur[q*4+0]=v.x; ur[q*4+1]=v.y; ur[q*4+2]=v.z; ur[q*4+3]=v.w;
      }
      float g0 = u16 * Kc[16], g1=0.f, g2=0.f, g3=0.f;
#pragma unroll
      for (int k = 0; k < 4; ++k) {
        g0 = fmaf(ur[k],    Kc[k],    g0);
        g1 = fmaf(ur[k+4],  Kc[k+4],  g1);
        g2 = fmaf(ur[k+8],  Kc[k+8],  g2);
        g3 = fmaf(ur[k+12], Kc[k+12], g3);
      }
      float sg = (g0 + g1) + (g2 + g3);
      vlane = q_l * rcpn(fmaxf(sg, TINYF));
      UVsh[tid] = vlane;
    }
    vm = vlane;
    // G = u * K * v
#pragma unroll
    for (int k = 0; k < 16; ++k) Gcol[k] = ur[k] * Kc[k] * vm;
    Gcol[16] = u16 * Kc[16] * vm;
  }

  // out[n,t] = sum_{i,l} (Mcol + delta) * G
  float a0 = 0.f, a1 = 0.f;
#pragma unroll
  for (int i = 0; i < K1; i += 2) a0 = fmaf(Mcol[i], Gcol[i], a0);
#pragma unroll
  for (int i = 1; i < K1; i += 2) a1 = fmaf(Mcol[i], Gcol[i], a1);
  float acc1 = a0 + a1;
#pragma unroll
  for (int i = 0; i < K1; ++i) {
    int rmi = rm[i];
    if (rmi) {
      asm volatile("" : "+s"(rmi));
      MASKED_ROWSUM(rmi, s)
      float g = s, acc = s * c2reg[0];
      WALK15()
      acc1 = fmaf(acc, Gcol[i], acc1);
    }
  }
  float accout = rsum16(acc1);
  if (l == 0) out[n*16 + t] = accout;
}

// ---------------------------------------------------------------------------
extern "C" void kernel_launch(void* const* d_in, const int* in_sizes, int n_in,
                              void* d_out, int out_size, void* d_ws, size_t ws_size,
                              hipStream_t stream) {
  const float* x          = (const float*)d_in[0];
  const float* adj        = (const float*)d_in[1];
  const int*   neighbors  = (const int*)  d_in[2];
  const float* templates_ = (const float*)d_in[3];
  const float* tfeat      = (const float*)d_in[4];
  const float* q0         = (const float*)d_in[5];
  const float* alpha0     = (const float*)d_in[6];
  float* out = (float*)d_out;

  float* ws        = (float*)d_ws;
  float* P         = ws;                         // 4096*256 floats
  unsigned* adjbits = (unsigned*)(P + 4096*256); // 4096*128 u32 = 2 MB
  float* xsq       = (float*)(adjbits + 4096*128);  // 4096
  float* tfsq      = xsq + 4096;                 // 256
  float* qmat      = tfsq + 256;                 // 256
  float* cq        = qmat + 256;                 // 256
  float* walpha    = cq + 256;                   // 1

  hipLaunchKernelGGL(prep_combined, dim3(PG_TOT), dim3(256), 0, stream,
                     x, adj, neighbors, templates_, tfeat, q0, alpha0,
                     P, adjbits, xsq, tfsq, qmat, cq, walpha);
  hipLaunchKernelGGL(ltfgw_main, dim3(4096), dim3(256), 0, stream,
                     P, adjbits, xsq, tfsq, qmat, cq, walpha, neighbors,
                     templates_, out);
}

// Round 4
// 177.239 us; speedup vs baseline: 1.0226x; 1.0226x over previous
//
#include <hip/hip_runtime.h>
#include <math.h>

// ---------------------------------------------------------------------------
// LTFGW: N=4096, K=16 (k1=17), T=16, NT=16, D=128, OUTER=3, INNER=5.
//
// R9: R8 post-mortem — branchless mbit path did NOT cut VALU busy (61us vs
//     R7's 60) and added 11us of stall; reverted main to R7 (empirical best).
//     REAL finding: ~98us of the 178 is OUTSIDE main, every round. The pole
//     is pgemm: 256 blocks on 256 CUs = 1 wave/SIMD, zero latency hiding on
//     a 64-deep serial LDS->FMA loop => ~90us for a 268-MFLOP GEMM.
//     Fix: 32x64 tiles (512 blocks, 2x4 micro-tile) — halves per-thread
//     serial work AND doubles co-residency. Predicted prep ~90 -> ~20us.
// R7 (kept): real uniform outer branch via volatile-asm pin on rmi; branchy
//     inner masked sum (empirically better than mbit/s_cselect).
// R6 (kept): binary adj -> packed 2MB bitset; cc1 = popcount/17.
// R2/R3 lesson (kept): no bulk LDS vector loads inside unrolled branches.
// ---------------------------------------------------------------------------

#define NN 4096
#define KNB 16
#define K1 17
#define TSTR 296      // Ksh per-template stride; 296%32==8 -> 2-way banks
#define TINYF 1e-16f

typedef const __attribute__((address_space(4))) float* c4fp;
typedef const __attribute__((address_space(4))) int*   c4ip;
__device__ __forceinline__ float sload(const float* p){ return *(c4fp)(unsigned long long)p; }
__device__ __forceinline__ int   sloadi(const int* p) { return *(c4ip)(unsigned long long)p; }

template<int CTRL>
__device__ __forceinline__ float dppmov(float x) {
  return __int_as_float(
      __builtin_amdgcn_update_dpp(0, __float_as_int(x), CTRL, 0xF, 0xF, true));
}
__device__ __forceinline__ float xor4v(float x) {        // xor4 = xor7 then xor3
  return dppmov<0x1B>(dppmov<0x141>(x));
}
__device__ __forceinline__ float rsum16(float x) {
  x += dppmov<0xB1>(x); x += dppmov<0x4E>(x);
  x += xor4v(x);        x += dppmov<0x128>(x);
  return x;
}
__device__ __forceinline__ float rmin16(float x) {
  x = fminf(x, dppmov<0xB1>(x)); x = fminf(x, dppmov<0x4E>(x));
  x = fminf(x, xor4v(x));        x = fminf(x, dppmov<0x128>(x));
  return x;
}
__device__ __forceinline__ float rmax16(float x) {
  x = fmaxf(x, dppmov<0xB1>(x)); x = fmaxf(x, dppmov<0x4E>(x));
  x = fmaxf(x, xor4v(x));        x = fmaxf(x, dppmov<0x128>(x));
  return x;
}
__device__ __forceinline__ float rcpn(float x) {   // rcp + 1 Newton step
  float r = __builtin_amdgcn_rcpf(x);
  return r * (2.f - x * r);
}

// cumulative XOR walk (verified R1/R4, absmax 0): after step r, g = src lane l^r
#define WSTEP(C, R) { g = dppmov<C>(g); acc = fmaf(g, c2reg[R], acc); }
#define WALK15() \
  WSTEP(0xB1,1)  WSTEP(0x1B,2)  WSTEP(0xB1,3)  WSTEP(0x141,4) \
  WSTEP(0xB1,5)  WSTEP(0x1B,6)  WSTEP(0xB1,7)  WSTEP(0x140,8) \
  WSTEP(0xB1,9)  WSTEP(0x1B,10) WSTEP(0xB1,11) WSTEP(0x141,12) \
  WSTEP(0xB1,13) WSTEP(0x1B,14) WSTEP(0xB1,15)

// ---------------------------------------------------------------------------
// prep_combined: one dispatch, block-range partitioned.
//   blocks [0,512)        : pgemm  P = x @ tf^T   (32x64 tile, 2 blocks/CU)
//   blocks [512,1536)     : xsq[n] = ||x[n]||^2   (trivial)
//   block  1536           : scalars (alpha,q,cq,tfsq)
//   blocks [1537,3585)    : adjbits, 2 rows/block (coalesced stream)
// ---------------------------------------------------------------------------
#define PG_GEMM  512
#define PG_XSQ   (PG_GEMM + 1024)       // 1536
#define PG_SCAL  PG_XSQ                  // block 1536
#define PG_ADJ   (PG_SCAL + 1)           // 1537
#define PG_TOT   (PG_ADJ + 2048)         // 3585

__global__ __launch_bounds__(256) void prep_combined(
    const float* __restrict__ x, const float* __restrict__ adj,
    const int* __restrict__ neighbors, const float* __restrict__ templates_,
    const float* __restrict__ tf, const float* __restrict__ q0,
    const float* __restrict__ alpha0,
    float* __restrict__ P, unsigned* __restrict__ adjbits,
    float* __restrict__ xsq,
    float* __restrict__ tfsq, float* __restrict__ qmat, float* __restrict__ cq,
    float* __restrict__ walpha) {
  __shared__ __align__(16) float smem[64*36 + 64*68];   // 26624 B arena
  const int b = blockIdx.x, tid = threadIdx.x;

  if (b < PG_GEMM) {
    // ---- pgemm: 32 rows x 64 cols per block, 2x4 per thread ----
    // 512 blocks -> 2 blocks/CU co-resident; per-thread serial fma halved
    // vs the old 64x64 tiling (which ran 1 wave/SIMD, latency-bound).
    float (*As)[36] = (float (*)[36])smem;            // As[d][row], d<64
    float (*Bs)[68] = (float (*)[68])(smem + 64*36);  // Bs[d][col], d<64
    int tx = tid & 15, ty = tid >> 4;
    int r0 = (b >> 2) * 32, c0 = (b & 3) * 64;
    float acc[2][4] = {};
    for (int h = 0; h < 2; ++h) {
      __syncthreads();
      // stage A: 32 rows x 64 d = 2048 floats = 2 float4/thread
#pragma unroll
      for (int q = 0; q < 2; ++q) {
        int f = tid + 256*q;
        int row = f >> 4, d4 = (f & 15) << 2;
        float4 a = *(const float4*)&x[(r0+row)*128 + h*64 + d4];
        As[d4+0][row]=a.x; As[d4+1][row]=a.y; As[d4+2][row]=a.z; As[d4+3][row]=a.w;
      }
      // stage B: 64 cols x 64 d = 4096 floats = 4 float4/thread
#pragma unroll
      for (int q = 0; q < 4; ++q) {
        int f = tid + 256*q;
        int row = f >> 4, d4 = (f & 15) << 2;
        float4 bb = *(const float4*)&tf[(c0+row)*128 + h*64 + d4];
        Bs[d4+0][row]=bb.x; Bs[d4+1][row]=bb.y; Bs[d4+2][row]=bb.z; Bs[d4+3][row]=bb.w;
      }
      __syncthreads();
#pragma unroll
      for (int d = 0; d < 64; ++d) {
        float2 a = *(const float2*)&As[d][ty*2];
        float4 bb = *(const float4*)&Bs[d][tx*4];
        float av[2]={a.x,a.y}, bv[4]={bb.x,bb.y,bb.z,bb.w};
#pragma unroll
        for (int i = 0; i < 2; ++i)
#pragma unroll
          for (int j = 0; j < 4; ++j) acc[i][j] = fmaf(av[i], bv[j], acc[i][j]);
      }
    }
#pragma unroll
    for (int i = 0; i < 2; ++i) {
      float4 o; o.x=acc[i][0]; o.y=acc[i][1]; o.z=acc[i][2]; o.w=acc[i][3];
      *(float4*)&P[(r0 + ty*2 + i)*256 + c0 + tx*4] = o;
    }
    return;
  }

  if (b < PG_XSQ) {
    // ---- xsq: 4 rows per block, 1 wave per row ----
    int n = (b - PG_GEMM)*4 + (tid >> 6), lane = tid & 63;
    float2 v = *(const float2*)&x[n*128 + lane*2];
    float s = fmaf(v.x, v.x, v.y*v.y);
    s += __shfl_xor(s,1); s += __shfl_xor(s,2);  s += __shfl_xor(s,4);
    s += __shfl_xor(s,8); s += __shfl_xor(s,16); s += __shfl_xor(s,32);
    if (lane == 0) xsq[n] = s;
    return;
  }

  if (b == PG_SCAL) {
    // ---- scalars: alpha, q=softmax(q0), cq, tfsq ----
    int t = tid >> 4, l = tid & 15;
    if (tid == 0) walpha[0] = 1.f / (1.f + expf(-alpha0[0]));
    float qr[16]; float mx = -3.0e38f;
#pragma unroll
    for (int m = 0; m < 16; ++m) { qr[m] = q0[t*16+m]; mx = fmaxf(mx, qr[m]); }
    float s = 0.f;
#pragma unroll
    for (int m = 0; m < 16; ++m) { qr[m] = expf(qr[m]-mx); s += qr[m]; }
    float inv = 1.f / s;
    qmat[tid] = qr[l] * inv;
    float c = 0.f;
#pragma unroll
    for (int m = 0; m < 16; ++m) {
      float c2 = templates_[t*256 + l*16 + m];
      c = fmaf(qr[m]*inv, c2*c2, c);
    }
    cq[tid] = c;
    float ts = 0.f;
#pragma unroll
    for (int dq = 0; dq < 32; ++dq) {
      float4 v = *(const float4*)&tf[tid*128 + dq*4];
      ts = fmaf(v.x,v.x,ts); ts = fmaf(v.y,v.y,ts);
      ts = fmaf(v.z,v.z,ts); ts = fmaf(v.w,v.w,ts);
    }
    tfsq[tid] = ts;
    return;
  }

  // ---- adjbits: 2 adj rows per block, coalesced stream -> packed bits ----
  {
    int row0 = (b - PG_ADJ) * 2;
    const float4* a0 = (const float4*)&adj[(long long)row0 * NN];
    const float4* a1 = (const float4*)&adj[(long long)(row0 + 1) * NN];
    float4 v0[4], v1[4];
#pragma unroll
    for (int q = 0; q < 4; ++q) v0[q] = a0[tid*4 + q];
#pragma unroll
    for (int q = 0; q < 4; ++q) v1[q] = a1[tid*4 + q];
    unsigned m0 = 0, m1 = 0;
#pragma unroll
    for (int q = 0; q < 4; ++q) {
      m0 |= (unsigned)(v0[q].x != 0.f) << (q*4 + 0);
      m0 |= (unsigned)(v0[q].y != 0.f) << (q*4 + 1);
      m0 |= (unsigned)(v0[q].z != 0.f) << (q*4 + 2);
      m0 |= (unsigned)(v0[q].w != 0.f) << (q*4 + 3);
      m1 |= (unsigned)(v1[q].x != 0.f) << (q*4 + 0);
      m1 |= (unsigned)(v1[q].y != 0.f) << (q*4 + 1);
      m1 |= (unsigned)(v1[q].z != 0.f) << (q*4 + 2);
      m1 |= (unsigned)(v1[q].w != 0.f) << (q*4 + 3);
    }
    unsigned o0 = (unsigned)__shfl_xor((int)m0, 1);
    unsigned o1 = (unsigned)__shfl_xor((int)m1, 1);
    if ((tid & 1) == 0) {
      adjbits[row0*128 + (tid >> 1)]       = m0 | (o0 << 16);
      adjbits[(row0 + 1)*128 + (tid >> 1)] = m1 | (o1 << 16);
    }
  }
}

// ---------------------------------------------------------------------------
// main: 1 block/node, 256 thr = 16 templates x 16 cols (R7-verified, exact).
// ---------------------------------------------------------------------------
__global__ __launch_bounds__(256, 2) void ltfgw_main(
    const float* __restrict__ P, const unsigned* __restrict__ adjbits,
    const float* __restrict__ xsq, const float* __restrict__ tfsq,
    const float* __restrict__ qmat, const float* __restrict__ cq,
    const float* __restrict__ walpha, const int* __restrict__ neighbors,
    const float* __restrict__ templates_, float* __restrict__ out) {
  __shared__ __align__(16) float Ksh[16 * TSTR];
  __shared__ __align__(16) float Ush[256];
  __shared__ __align__(16) float Vsh[256];
  __shared__ int nb_sh[20];
  __shared__ int rm_sh[20];

  const int tid = threadIdx.x;
  const int t = tid >> 4, l = tid & 15;
  const int n = blockIdx.x;

  // ---- prologue: build 17 per-row C1 bitmasks from the packed bitset ----
  if (tid < K1) {
    nb_sh[tid] = (tid == 0) ? n : neighbors[n*KNB + tid - 1];
    rm_sh[tid] = 0;
  }
  __syncthreads();
  for (unsigned e = tid; e < 289; e += 256) {
    unsigned i = e / 17u, j = e % 17u;
    int ni = nb_sh[i], nj = nb_sh[j];
    unsigned w = adjbits[ni*128 + (nj >> 5)];
    if ((w >> (nj & 31)) & 1u) atomicOr(&rm_sh[i], 1 << j);
  }
  __syncthreads();

  int rm[K1];
  int nbk[K1];
#pragma unroll
  for (int k = 0; k < K1; ++k) {
    rm[k]  = __builtin_amdgcn_readfirstlane(rm_sh[k]);
    nbk[k] = __builtin_amdgcn_readfirstlane(nb_sh[k]);
  }

  const float alpha = sload(walpha);
  const float oma = 1.f - alpha;
  const float na2 = -2.f * alpha;

  const float tfsq_l = tfsq[tid];
  const float cq_l   = cq[tid];
  const float q_l    = qmat[tid];

  // Mcol = (1-a)*M + a*cC ; cc1 = popcount(row)/17 since C1 is binary.
  float Mcol[K1];
#pragma unroll
  for (int k = 0; k < K1; ++k) {
    float xs  = sload(xsq + nbk[k]);
    float cc1 = (float)__popc((unsigned)rm[k]) * (1.f/17.f);
    float pv  = P[nbk[k]*256 + tid];
    Mcol[k] = oma * (xs + tfsq_l - 2.f*pv) + alpha * (cc1 + cq_l);
  }

  // c2reg[r] = -2a * C2[t][l][l^r]  (pre-rotated for the XOR walk)
  float c2reg[16];
#pragma unroll
  for (int r = 0; r < 16; ++r)
    c2reg[r] = na2 * templates_[t*256 + l*16 + (l ^ r)];

  // G[j][l] in registers; init p*q
  float Gcol[K1];
#pragma unroll
  for (int j = 0; j < K1; ++j) Gcol[j] = (1.f/17.f) * q_l;

  const int tb = t * TSTR;
  float ur[16], u16 = 0.f, vm = 1.f;

#pragma unroll 1
  for (int outer = 0; outer < 3; ++outer) {
    // grad rows -> Kc[]; only C1-nonzero rows (~2.3/17) do bit-sum + walk.
    // The volatile asm pins rmi inside the branch: the masked sum consumes
    // the asm output and the walk consumes the sum, so NOTHING here can be
    // speculated/if-converted out of the s_cbranch (uniform, SGPR mask).
    float Kc[K1];
    float lo = 3.0e38f, hi = -3.0e38f;
#pragma unroll
    for (int i = 0; i < K1; ++i) {
      float gr = Mcol[i];
      int rmi = rm[i];
      if (rmi) {
        asm volatile("" : "+s"(rmi));
        float s = 0.f;
#pragma unroll
        for (int j = 0; j < K1; ++j)
          if (rmi & (1 << j)) s += Gcol[j];   // == fmaf({0,1},G,s) exactly
        float g = s, acc = s * c2reg[0];
        WALK15()
        gr += acc;
      }
      Kc[i] = gr;
      lo = fminf(lo, gr); hi = fmaxf(hi, gr);
    }
    lo = rmin16(lo); hi = rmax16(hi);
    float eps = 0.1f * (hi - lo) + TINYF;
    float sc = 1.4426950408889634f * __builtin_amdgcn_rcpf(eps);
    float nsc = -sc, losc = lo * sc;
#pragma unroll
    for (int i = 0; i < K1; ++i) {
      Kc[i] = __builtin_amdgcn_exp2f(fmaf(Kc[i], nsc, losc));
      Ksh[tb + i*17 + l] = Kc[i];           // transpose write (same wave)
    }
    // row l of K for the u-update
    float Krow[16];
#pragma unroll
    for (int jq = 0; jq < 4; ++jq) {
      float4 v = *(const float4*)&Ksh[tb + l*17 + jq*4];
      Krow[jq*4+0]=v.x; Krow[jq*4+1]=v.y; Krow[jq*4+2]=v.z; Krow[jq*4+3]=v.w;
    }

    // Sinkhorn: 5 iters (u then v), v0 = 1
    float vlane = 1.f;
    Vsh[tid] = 1.f;
#pragma unroll 1
    for (int it = 0; it < 5; ++it) {
      float vr[16];
#pragma unroll
      for (int q = 0; q < 4; ++q) {
        float4 v = *(const float4*)&Vsh[t*16 + q*4];
        vr[q*4+0]=v.x; vr[q*4+1]=v.y; vr[q*4+2]=v.z; vr[q*4+3]=v.w;
      }
      float w = 0.f;
#pragma unroll
      for (int j = 0; j < 16; ++j) w = fmaf(Krow[j], vr[j], w);
      float w16 = rsum16(Kc[16] * vlane);          // row 16 via DPP
      float um = (1.f/17.f) * rcpn(fmaxf(w,   TINYF));
      u16      = (1.f/17.f) * rcpn(fmaxf(w16, TINYF));
      Ush[tid] = um;
#pragma unroll
      for (int q = 0; q < 4; ++q) {
        float4 v = *(const float4*)&Ush[t*16 + q*4];
        ur[q*4+0]=v.x; ur[q*4+1]=v.y; ur[q*4+2]=v.z; ur[q*4+3]=v.w;
      }
      float sg = u16 * Kc[16];
#pragma unroll
      for (int k = 0; k < 16; ++k) sg = fmaf(ur[k], Kc[k], sg);
      vlane = q_l * rcpn(fmaxf(sg, TINYF));
      Vsh[tid] = vlane;
    }
    vm = vlane;
    // G = u * K * v
#pragma unroll
    for (int k = 0; k < 16; ++k) Gcol[k] = ur[k] * Kc[k] * vm;
    Gcol[16] = u16 * Kc[16] * vm;
  }

  // out[n,t] = sum_{i,l} (Mcol + delta) * G
  float acc1 = 0.f;
#pragma unroll
  for (int i = 0; i < K1; ++i) acc1 = fmaf(Mcol[i], Gcol[i], acc1);
#pragma unroll
  for (int i = 0; i < K1; ++i) {
    int rmi = rm[i];
    if (rmi) {
      asm volatile("" : "+s"(rmi));
      float s = 0.f;
#pragma unroll
      for (int j = 0; j < K1; ++j)
        if (rmi & (1 << j)) s += Gcol[j];
      float g = s, acc = s * c2reg[0];
      WALK15()
      acc1 = fmaf(acc, Gcol[i], acc1);
    }
  }
  float accout = rsum16(acc1);
  if (l == 0) out[n*16 + t] = accout;
}

// ---------------------------------------------------------------------------
extern "C" void kernel_launch(void* const* d_in, const int* in_sizes, int n_in,
                              void* d_out, int out_size, void* d_ws, size_t ws_size,
                              hipStream_t stream) {
  const float* x          = (const float*)d_in[0];
  const float* adj        = (const float*)d_in[1];
  const int*   neighbors  = (const int*)  d_in[2];
  const float* templates_ = (const float*)d_in[3];
  const float* tfeat      = (const float*)d_in[4];
  const float* q0         = (const float*)d_in[5];
  const float* alpha0     = (const float*)d_in[6];
  float* out = (float*)d_out;

  float* ws        = (float*)d_ws;
  float* P         = ws;                         // 4096*256 floats
  unsigned* adjbits = (unsigned*)(P + 4096*256); // 4096*128 u32 = 2 MB
  float* xsq       = (float*)(adjbits + 4096*128);  // 4096
  float* tfsq      = xsq + 4096;                 // 256
  float* qmat      = tfsq + 256;                 // 256
  float* cq        = qmat + 256;                 // 256
  float* walpha    = cq + 256;                   // 1

  hipLaunchKernelGGL(prep_combined, dim3(PG_TOT), dim3(256), 0, stream,
                     x, adj, neighbors, templates_, tfeat, q0, alpha0,
                     P, adjbits, xsq, tfsq, qmat, cq, walpha);
  hipLaunchKernelGGL(ltfgw_main, dim3(4096), dim3(256), 0, stream,
                     P, adjbits, xsq, tfsq, qmat, cq, walpha, neighbors,
                     templates_, out);
}

// Round 5
// 175.042 us; speedup vs baseline: 1.0355x; 1.0126x over previous
//
#include <hip/hip_runtime.h>
#include <math.h>

// ---------------------------------------------------------------------------
// LTFGW: N=4096, K=16 (k1=17), T=16, NT=16, D=128, OUTER=3, INNER=5.
//
// R10: discriminating experiment. R9's pgemm re-tile was NULL (178->177) =>
//     "pgemm is the pole" falsified. ~96us sits outside main every round,
//     across two totally different preps. Either the adjbits stage (64MB
//     stream + 2048 blocks + serialized dependency) is the pole, or it's
//     fixed harness overhead. Test: DELETE the adjbits stage; fuse the 17x17
//     gather into main's prologue as direct adj loads (v!=0 -> same masks,
//     bit-identical). 289 scattered loads/block issue at block start and
//     hide under main's 80us VALU body; adj is L3-resident after warmup.
//     Prep is now 1537 blocks, ~4MB traffic (~10us model).
//     If total -> ~105us: prep was the pole. If ~170us: harness overhead,
//     and future rounds target main only.
// R9 (kept): 32x64 pgemm tiles (512 blocks, 2 blocks/CU).
// R7 (kept): real uniform outer branch via volatile-asm pin on rmi; branchy
//     inner masked sum. Main body R7-exact.
// R6 (kept): binary adj -> row bitmasks; cc1 = popcount/17.
// ---------------------------------------------------------------------------

#define NN 4096
#define KNB 16
#define K1 17
#define TSTR 296      // Ksh per-template stride; 296%32==8 -> 2-way banks
#define TINYF 1e-16f

typedef const __attribute__((address_space(4))) float* c4fp;
typedef const __attribute__((address_space(4))) int*   c4ip;
__device__ __forceinline__ float sload(const float* p){ return *(c4fp)(unsigned long long)p; }
__device__ __forceinline__ int   sloadi(const int* p) { return *(c4ip)(unsigned long long)p; }

template<int CTRL>
__device__ __forceinline__ float dppmov(float x) {
  return __int_as_float(
      __builtin_amdgcn_update_dpp(0, __float_as_int(x), CTRL, 0xF, 0xF, true));
}
__device__ __forceinline__ float xor4v(float x) {        // xor4 = xor7 then xor3
  return dppmov<0x1B>(dppmov<0x141>(x));
}
__device__ __forceinline__ float rsum16(float x) {
  x += dppmov<0xB1>(x); x += dppmov<0x4E>(x);
  x += xor4v(x);        x += dppmov<0x128>(x);
  return x;
}
__device__ __forceinline__ float rmin16(float x) {
  x = fminf(x, dppmov<0xB1>(x)); x = fminf(x, dppmov<0x4E>(x));
  x = fminf(x, xor4v(x));        x = fminf(x, dppmov<0x128>(x));
  return x;
}
__device__ __forceinline__ float rmax16(float x) {
  x = fmaxf(x, dppmov<0xB1>(x)); x = fmaxf(x, dppmov<0x4E>(x));
  x = fmaxf(x, xor4v(x));        x = fmaxf(x, dppmov<0x128>(x));
  return x;
}
__device__ __forceinline__ float rcpn(float x) {   // rcp + 1 Newton step
  float r = __builtin_amdgcn_rcpf(x);
  return r * (2.f - x * r);
}

// cumulative XOR walk (verified R1/R4, absmax 0): after step r, g = src lane l^r
#define WSTEP(C, R) { g = dppmov<C>(g); acc = fmaf(g, c2reg[R], acc); }
#define WALK15() \
  WSTEP(0xB1,1)  WSTEP(0x1B,2)  WSTEP(0xB1,3)  WSTEP(0x141,4) \
  WSTEP(0xB1,5)  WSTEP(0x1B,6)  WSTEP(0xB1,7)  WSTEP(0x140,8) \
  WSTEP(0xB1,9)  WSTEP(0x1B,10) WSTEP(0xB1,11) WSTEP(0x141,12) \
  WSTEP(0xB1,13) WSTEP(0x1B,14) WSTEP(0xB1,15)

// ---------------------------------------------------------------------------
// prep_combined: one dispatch, block-range partitioned.
//   blocks [0,512)        : pgemm  P = x @ tf^T   (32x64 tile, 2 blocks/CU)
//   blocks [512,1536)     : xsq[n] = ||x[n]||^2   (trivial)
//   block  1536           : scalars (alpha,q,cq,tfsq)
// ---------------------------------------------------------------------------
#define PG_GEMM  512
#define PG_XSQ   (PG_GEMM + 1024)       // 1536
#define PG_SCAL  PG_XSQ                  // block 1536
#define PG_TOT   (PG_SCAL + 1)           // 1537

__global__ __launch_bounds__(256) void prep_combined(
    const float* __restrict__ x,
    const float* __restrict__ templates_,
    const float* __restrict__ tf, const float* __restrict__ q0,
    const float* __restrict__ alpha0,
    float* __restrict__ P,
    float* __restrict__ xsq,
    float* __restrict__ tfsq, float* __restrict__ qmat, float* __restrict__ cq,
    float* __restrict__ walpha) {
  __shared__ __align__(16) float smem[64*36 + 64*68];   // 26624 B arena
  const int b = blockIdx.x, tid = threadIdx.x;

  if (b < PG_GEMM) {
    // ---- pgemm: 32 rows x 64 cols per block, 2x4 per thread ----
    float (*As)[36] = (float (*)[36])smem;            // As[d][row], d<64
    float (*Bs)[68] = (float (*)[68])(smem + 64*36);  // Bs[d][col], d<64
    int tx = tid & 15, ty = tid >> 4;
    int r0 = (b >> 2) * 32, c0 = (b & 3) * 64;
    float acc[2][4] = {};
    for (int h = 0; h < 2; ++h) {
      __syncthreads();
      // stage A: 32 rows x 64 d = 2048 floats = 2 float4/thread
#pragma unroll
      for (int q = 0; q < 2; ++q) {
        int f = tid + 256*q;
        int row = f >> 4, d4 = (f & 15) << 2;
        float4 a = *(const float4*)&x[(r0+row)*128 + h*64 + d4];
        As[d4+0][row]=a.x; As[d4+1][row]=a.y; As[d4+2][row]=a.z; As[d4+3][row]=a.w;
      }
      // stage B: 64 cols x 64 d = 4096 floats = 4 float4/thread
#pragma unroll
      for (int q = 0; q < 4; ++q) {
        int f = tid + 256*q;
        int row = f >> 4, d4 = (f & 15) << 2;
        float4 bb = *(const float4*)&tf[(c0+row)*128 + h*64 + d4];
        Bs[d4+0][row]=bb.x; Bs[d4+1][row]=bb.y; Bs[d4+2][row]=bb.z; Bs[d4+3][row]=bb.w;
      }
      __syncthreads();
#pragma unroll
      for (int d = 0; d < 64; ++d) {
        float2 a = *(const float2*)&As[d][ty*2];
        float4 bb = *(const float4*)&Bs[d][tx*4];
        float av[2]={a.x,a.y}, bv[4]={bb.x,bb.y,bb.z,bb.w};
#pragma unroll
        for (int i = 0; i < 2; ++i)
#pragma unroll
          for (int j = 0; j < 4; ++j) acc[i][j] = fmaf(av[i], bv[j], acc[i][j]);
      }
    }
#pragma unroll
    for (int i = 0; i < 2; ++i) {
      float4 o; o.x=acc[i][0]; o.y=acc[i][1]; o.z=acc[i][2]; o.w=acc[i][3];
      *(float4*)&P[(r0 + ty*2 + i)*256 + c0 + tx*4] = o;
    }
    return;
  }

  if (b < PG_XSQ) {
    // ---- xsq: 4 rows per block, 1 wave per row ----
    int n = (b - PG_GEMM)*4 + (tid >> 6), lane = tid & 63;
    float2 v = *(const float2*)&x[n*128 + lane*2];
    float s = fmaf(v.x, v.x, v.y*v.y);
    s += __shfl_xor(s,1); s += __shfl_xor(s,2);  s += __shfl_xor(s,4);
    s += __shfl_xor(s,8); s += __shfl_xor(s,16); s += __shfl_xor(s,32);
    if (lane == 0) xsq[n] = s;
    return;
  }

  if (b == PG_SCAL) {
    // ---- scalars: alpha, q=softmax(q0), cq, tfsq ----
    int t = tid >> 4, l = tid & 15;
    if (tid == 0) walpha[0] = 1.f / (1.f + expf(-alpha0[0]));
    float qr[16]; float mx = -3.0e38f;
#pragma unroll
    for (int m = 0; m < 16; ++m) { qr[m] = q0[t*16+m]; mx = fmaxf(mx, qr[m]); }
    float s = 0.f;
#pragma unroll
    for (int m = 0; m < 16; ++m) { qr[m] = expf(qr[m]-mx); s += qr[m]; }
    float inv = 1.f / s;
    qmat[tid] = qr[l] * inv;
    float c = 0.f;
#pragma unroll
    for (int m = 0; m < 16; ++m) {
      float c2 = templates_[t*256 + l*16 + m];
      c = fmaf(qr[m]*inv, c2*c2, c);
    }
    cq[tid] = c;
    float ts = 0.f;
#pragma unroll
    for (int dq = 0; dq < 32; ++dq) {
      float4 v = *(const float4*)&tf[tid*128 + dq*4];
      ts = fmaf(v.x,v.x,ts); ts = fmaf(v.y,v.y,ts);
      ts = fmaf(v.z,v.z,ts); ts = fmaf(v.w,v.w,ts);
    }
    tfsq[tid] = ts;
    return;
  }
}

// ---------------------------------------------------------------------------
// main: 1 block/node, 256 thr = 16 templates x 16 cols (R7-verified core).
// Prologue: 289 direct adj gathers (4B, L3-resident after warmup) -> 17
// per-row bitmasks via LDS atomicOr. Issued at block start, latency hides
// under the 80us VALU-bound body.
// ---------------------------------------------------------------------------
__global__ __launch_bounds__(256, 2) void ltfgw_main(
    const float* __restrict__ P, const float* __restrict__ adj,
    const float* __restrict__ xsq, const float* __restrict__ tfsq,
    const float* __restrict__ qmat, const float* __restrict__ cq,
    const float* __restrict__ walpha, const int* __restrict__ neighbors,
    const float* __restrict__ templates_, float* __restrict__ out) {
  __shared__ __align__(16) float Ksh[16 * TSTR];
  __shared__ __align__(16) float Ush[256];
  __shared__ __align__(16) float Vsh[256];
  __shared__ int nb_sh[20];
  __shared__ int rm_sh[20];

  const int tid = threadIdx.x;
  const int t = tid >> 4, l = tid & 15;
  const int n = blockIdx.x;

  // ---- prologue: gather the 17x17 C1 bit-matrix directly from adj ----
  if (tid < K1) {
    nb_sh[tid] = (tid == 0) ? n : neighbors[n*KNB + tid - 1];
    rm_sh[tid] = 0;
  }
  __syncthreads();
  for (unsigned e = tid; e < 289; e += 256) {
    unsigned i = e / 17u, j = e % 17u;
    int ni = nb_sh[i], nj = nb_sh[j];
    float v = adj[ni*NN + nj];            // {0.0f, 1.0f} exactly
    if (v != 0.f) atomicOr(&rm_sh[i], 1 << j);
  }
  __syncthreads();

  int rm[K1];
  int nbk[K1];
#pragma unroll
  for (int k = 0; k < K1; ++k) {
    rm[k]  = __builtin_amdgcn_readfirstlane(rm_sh[k]);
    nbk[k] = __builtin_amdgcn_readfirstlane(nb_sh[k]);
  }

  const float alpha = sload(walpha);
  const float oma = 1.f - alpha;
  const float na2 = -2.f * alpha;

  const float tfsq_l = tfsq[tid];
  const float cq_l   = cq[tid];
  const float q_l    = qmat[tid];

  // Mcol = (1-a)*M + a*cC ; cc1 = popcount(row)/17 since C1 is binary.
  float Mcol[K1];
#pragma unroll
  for (int k = 0; k < K1; ++k) {
    float xs  = sload(xsq + nbk[k]);
    float cc1 = (float)__popc((unsigned)rm[k]) * (1.f/17.f);
    float pv  = P[nbk[k]*256 + tid];
    Mcol[k] = oma * (xs + tfsq_l - 2.f*pv) + alpha * (cc1 + cq_l);
  }

  // c2reg[r] = -2a * C2[t][l][l^r]  (pre-rotated for the XOR walk)
  float c2reg[16];
#pragma unroll
  for (int r = 0; r < 16; ++r)
    c2reg[r] = na2 * templates_[t*256 + l*16 + (l ^ r)];

  // G[j][l] in registers; init p*q
  float Gcol[K1];
#pragma unroll
  for (int j = 0; j < K1; ++j) Gcol[j] = (1.f/17.f) * q_l;

  const int tb = t * TSTR;
  float ur[16], u16 = 0.f, vm = 1.f;

#pragma unroll 1
  for (int outer = 0; outer < 3; ++outer) {
    // grad rows -> Kc[]; only C1-nonzero rows (~2.3/17) do bit-sum + walk.
    // The volatile asm pins rmi inside the branch: the masked sum consumes
    // the asm output and the walk consumes the sum, so NOTHING here can be
    // speculated/if-converted out of the s_cbranch (uniform, SGPR mask).
    float Kc[K1];
    float lo = 3.0e38f, hi = -3.0e38f;
#pragma unroll
    for (int i = 0; i < K1; ++i) {
      float gr = Mcol[i];
      int rmi = rm[i];
      if (rmi) {
        asm volatile("" : "+s"(rmi));
        float s = 0.f;
#pragma unroll
        for (int j = 0; j < K1; ++j)
          if (rmi & (1 << j)) s += Gcol[j];   // == fmaf({0,1},G,s) exactly
        float g = s, acc = s * c2reg[0];
        WALK15()
        gr += acc;
      }
      Kc[i] = gr;
      lo = fminf(lo, gr); hi = fmaxf(hi, gr);
    }
    lo = rmin16(lo); hi = rmax16(hi);
    float eps = 0.1f * (hi - lo) + TINYF;
    float sc = 1.4426950408889634f * __builtin_amdgcn_rcpf(eps);
    float nsc = -sc, losc = lo * sc;
#pragma unroll
    for (int i = 0; i < K1; ++i) {
      Kc[i] = __builtin_amdgcn_exp2f(fmaf(Kc[i], nsc, losc));
      Ksh[tb + i*17 + l] = Kc[i];           // transpose write (same wave)
    }
    // row l of K for the u-update
    float Krow[16];
#pragma unroll
    for (int jq = 0; jq < 4; ++jq) {
      float4 v = *(const float4*)&Ksh[tb + l*17 + jq*4];
      Krow[jq*4+0]=v.x; Krow[jq*4+1]=v.y; Krow[jq*4+2]=v.z; Krow[jq*4+3]=v.w;
    }

    // Sinkhorn: 5 iters (u then v), v0 = 1
    float vlane = 1.f;
    Vsh[tid] = 1.f;
#pragma unroll 1
    for (int it = 0; it < 5; ++it) {
      float vr[16];
#pragma unroll
      for (int q = 0; q < 4; ++q) {
        float4 v = *(const float4*)&Vsh[t*16 + q*4];
        vr[q*4+0]=v.x; vr[q*4+1]=v.y; vr[q*4+2]=v.z; vr[q*4+3]=v.w;
      }
      float w = 0.f;
#pragma unroll
      for (int j = 0; j < 16; ++j) w = fmaf(Krow[j], vr[j], w);
      float w16 = rsum16(Kc[16] * vlane);          // row 16 via DPP
      float um = (1.f/17.f) * rcpn(fmaxf(w,   TINYF));
      u16      = (1.f/17.f) * rcpn(fmaxf(w16, TINYF));
      Ush[tid] = um;
#pragma unroll
      for (int q = 0; q < 4; ++q) {
        float4 v = *(const float4*)&Ush[t*16 + q*4];
        ur[q*4+0]=v.x; ur[q*4+1]=v.y; ur[q*4+2]=v.z; ur[q*4+3]=v.w;
      }
      float sg = u16 * Kc[16];
#pragma unroll
      for (int k = 0; k < 16; ++k) sg = fmaf(ur[k], Kc[k], sg);
      vlane = q_l * rcpn(fmaxf(sg, TINYF));
      Vsh[tid] = vlane;
    }
    vm = vlane;
    // G = u * K * v
#pragma unroll
    for (int k = 0; k < 16; ++k) Gcol[k] = ur[k] * Kc[k] * vm;
    Gcol[16] = u16 * Kc[16] * vm;
  }

  // out[n,t] = sum_{i,l} (Mcol + delta) * G
  float acc1 = 0.f;
#pragma unroll
  for (int i = 0; i < K1; ++i) acc1 = fmaf(Mcol[i], Gcol[i], acc1);
#pragma unroll
  for (int i = 0; i < K1; ++i) {
    int rmi = rm[i];
    if (rmi) {
      asm volatile("" : "+s"(rmi));
      float s = 0.f;
#pragma unroll
      for (int j = 0; j < K1; ++j)
        if (rmi & (1 << j)) s += Gcol[j];
      float g = s, acc = s * c2reg[0];
      WALK15()
      acc1 = fmaf(acc, Gcol[i], acc1);
    }
  }
  float accout = rsum16(acc1);
  if (l == 0) out[n*16 + t] = accout;
}

// ---------------------------------------------------------------------------
extern "C" void kernel_launch(void* const* d_in, const int* in_sizes, int n_in,
                              void* d_out, int out_size, void* d_ws, size_t ws_size,
                              hipStream_t stream) {
  const float* x          = (const float*)d_in[0];
  const float* adj        = (const float*)d_in[1];
  const int*   neighbors  = (const int*)  d_in[2];
  const float* templates_ = (const float*)d_in[3];
  const float* tfeat      = (const float*)d_in[4];
  const float* q0         = (const float*)d_in[5];
  const float* alpha0     = (const float*)d_in[6];
  float* out = (float*)d_out;

  float* ws     = (float*)d_ws;
  float* P      = ws;                       // 4096*256 floats
  float* xsq    = P + 4096*256;             // 4096
  float* tfsq   = xsq + 4096;               // 256
  float* qmat   = tfsq + 256;               // 256
  float* cq     = qmat + 256;               // 256
  float* walpha = cq + 256;                 // 1

  hipLaunchKernelGGL(prep_combined, dim3(PG_TOT), dim3(256), 0, stream,
                     x, templates_, tfeat, q0, alpha0,
                     P, xsq, tfsq, qmat, cq, walpha);
  hipLaunchKernelGGL(ltfgw_main, dim3(4096), dim3(256), 0, stream,
                     P, adj, xsq, tfsq, qmat, cq, walpha, neighbors,
                     templates_, out);
}